// Round 1
// baseline (1116.126 us; speedup 1.0000x reference)
//
#include <hip/hip_runtime.h>
#include <cstddef>

#define DD 128
#define EPS 1e-5f

// ---------------- CSR build ----------------

__global__ void hist_kernel(const int* __restrict__ row, int* __restrict__ deg, int E) {
    int e = blockIdx.x * blockDim.x + threadIdx.x;
    if (e < E) atomicAdd(&deg[row[e]], 1);
}

// per-block inclusive scan (1024) -> tmp, block total -> bsum
__global__ void scanA_kernel(const int* __restrict__ deg, int* __restrict__ tmp,
                             int* __restrict__ bsum, int n) {
    __shared__ int s[1024];
    int tid = threadIdx.x;
    int gid = blockIdx.x * 1024 + tid;
    int v = (gid < n) ? deg[gid] : 0;
    s[tid] = v;
    __syncthreads();
    for (int off = 1; off < 1024; off <<= 1) {
        int t = s[tid];
        int u = (tid >= off) ? s[tid - off] : 0;
        __syncthreads();
        s[tid] = t + u;
        __syncthreads();
    }
    if (gid < n) tmp[gid] = s[tid];
    if (tid == 1023) bsum[blockIdx.x] = s[1023];
}

// scan the (<=128) block sums -> exclusive boff; write row_start[N] = total
__global__ void scanB_kernel(const int* __restrict__ bsum, int* __restrict__ boff,
                             int* __restrict__ row_start, int nb, int n) {
    __shared__ int s[128];
    int tid = threadIdx.x;
    int v = (tid < nb) ? bsum[tid] : 0;
    s[tid] = v;
    __syncthreads();
    for (int off = 1; off < 128; off <<= 1) {
        int t = s[tid];
        int u = (tid >= off) ? s[tid - off] : 0;
        __syncthreads();
        s[tid] = t + u;
        __syncthreads();
    }
    if (tid < nb) boff[tid] = s[tid] - v;
    if (tid == nb - 1) row_start[n] = s[tid];
}

__global__ void scanC_kernel(const int* __restrict__ deg, const int* __restrict__ tmp,
                             const int* __restrict__ boff, int* __restrict__ row_start,
                             int* __restrict__ cursor, int n) {
    int gid = blockIdx.x * 1024 + threadIdx.x;
    if (gid < n) {
        int rs = tmp[gid] - deg[gid] + boff[blockIdx.x];
        row_start[gid] = rs;
        cursor[gid] = rs;
    }
}

__global__ void scatter_kernel(const int* __restrict__ row, const int* __restrict__ col,
                               const float* __restrict__ ew, int* __restrict__ cursor,
                               int* __restrict__ csr_col, float* __restrict__ csr_w, int E) {
    int e = blockIdx.x * blockDim.x + threadIdx.x;
    if (e < E) {
        int r = row[e];
        int p = atomicAdd(&cursor[r], 1);
        csr_col[p] = col[e];
        csr_w[p] = ew[e];
    }
}

// ---------------- GEMM (optionally fused BN+ReLU on the input) ----------------
// out[n, c] = sum_k f(A[n,k]) * W[k,c] + bias[c],  f = identity or relu(a*scale_k+shift_k)
// Tile 128x128, block 256 threads, 8x8 micro-tile, K-chunks of 32.

__global__ __launch_bounds__(256) void gemm_bn_kernel(
    const float* __restrict__ A, const float* __restrict__ W,
    const float* __restrict__ bias,
    const float* __restrict__ scale, const float* __restrict__ shift,
    int doBN, float* __restrict__ out, int nrows)
{
    __shared__ float Ast[32][132];   // [k][m], pad 132 keeps 16B alignment, reduces store conflicts
    __shared__ float Ws[32][128];    // [k][n]

    const int tid  = threadIdx.x;
    const int row0 = blockIdx.x * 128;
    const int tc   = (tid & 15) * 8;   // output col start
    const int tr   = (tid >> 4) * 8;   // output row start (within tile)

    float acc[8][8];
    #pragma unroll
    for (int i = 0; i < 8; ++i)
        #pragma unroll
        for (int j = 0; j < 8; ++j) acc[i][j] = 0.f;

    const int lk = tid & 7;    // which float4 of the 32-wide k chunk
    const int lr = tid >> 3;   // 0..31 row in pass

    for (int kc = 0; kc < 128; kc += 32) {
        // stage A transposed (with optional BN+ReLU)
        #pragma unroll
        for (int p = 0; p < 4; ++p) {
            int r = lr + p * 32;
            int grow = row0 + r;
            float4 v = make_float4(0.f, 0.f, 0.f, 0.f);
            if (grow < nrows)
                v = *(const float4*)(A + (size_t)grow * DD + kc + lk * 4);
            if (doBN) {
                int k = kc + lk * 4;
                v.x = fmaxf(0.f, v.x * scale[k + 0] + shift[k + 0]);
                v.y = fmaxf(0.f, v.y * scale[k + 1] + shift[k + 1]);
                v.z = fmaxf(0.f, v.z * scale[k + 2] + shift[k + 2]);
                v.w = fmaxf(0.f, v.w * scale[k + 3] + shift[k + 3]);
            }
            Ast[lk * 4 + 0][r] = v.x;
            Ast[lk * 4 + 1][r] = v.y;
            Ast[lk * 4 + 2][r] = v.z;
            Ast[lk * 4 + 3][r] = v.w;
        }
        // stage W
        {
            int wc = (tid & 31) * 4;
            int wr = tid >> 5;
            #pragma unroll
            for (int p = 0; p < 4; ++p) {
                int r = wr + p * 8;
                *(float4*)&Ws[r][wc] = *(const float4*)(W + (size_t)(kc + r) * DD + wc);
            }
        }
        __syncthreads();
        #pragma unroll
        for (int k = 0; k < 32; ++k) {
            float a[8], b[8];
            *(float4*)&a[0] = *(const float4*)&Ast[k][tr];
            *(float4*)&a[4] = *(const float4*)&Ast[k][tr + 4];
            *(float4*)&b[0] = *(const float4*)&Ws[k][tc];
            *(float4*)&b[4] = *(const float4*)&Ws[k][tc + 4];
            #pragma unroll
            for (int i = 0; i < 8; ++i)
                #pragma unroll
                for (int j = 0; j < 8; ++j)
                    acc[i][j] += a[i] * b[j];
        }
        __syncthreads();
    }

    float bv[8];
    *(float4*)&bv[0] = *(const float4*)&bias[tc];
    *(float4*)&bv[4] = *(const float4*)&bias[tc + 4];
    #pragma unroll
    for (int i = 0; i < 8; ++i) {
        int grow = row0 + tr + i;
        if (grow < nrows) {
            float o[8];
            #pragma unroll
            for (int j = 0; j < 8; ++j) o[j] = acc[i][j] + bv[j];
            *(float4*)(out + (size_t)grow * DD + tc)     = *(float4*)&o[0];
            *(float4*)(out + (size_t)grow * DD + tc + 4) = *(float4*)&o[4];
        }
    }
}

// ---------------- SpMM: one block (128 threads) per row ----------------

__global__ void spmm_kernel(const float* __restrict__ H, const int* __restrict__ row_start,
                            const int* __restrict__ csr_col, const float* __restrict__ csr_w,
                            float* __restrict__ S) {
    int r = blockIdx.x;
    int c = threadIdx.x;
    int e0 = row_start[r];
    int e1 = row_start[r + 1];
    float acc = 0.f;
    for (int e = e0; e < e1; ++e) {
        int col = csr_col[e];
        float w = csr_w[e];
        acc += w * H[(size_t)col * DD + c];
    }
    S[(size_t)r * DD + c] = acc;
}

// ---------------- BatchNorm stats + finalize ----------------

__global__ void bn_stats_kernel(const float* __restrict__ S, float* __restrict__ sums, int n) {
    __shared__ float ls[256], ls2[256];
    int tid = threadIdx.x;
    int c = tid & 127;
    float s = 0.f, s2 = 0.f;
    size_t total = (size_t)n * DD;
    for (size_t i = (size_t)blockIdx.x * 256 + tid; i < total; i += (size_t)256 * 256) {
        float v = S[i];
        s += v;
        s2 += v * v;
    }
    ls[tid] = s;
    ls2[tid] = s2;
    __syncthreads();
    if (tid < 128) {
        s  = ls[tid] + ls[tid + 128];
        s2 = ls2[tid] + ls2[tid + 128];
        atomicAdd(&sums[c], s);
        atomicAdd(&sums[128 + c], s2);
    }
}

__global__ void bn_final_kernel(const float* __restrict__ sums, const float* __restrict__ g,
                                const float* __restrict__ be, float* __restrict__ scl,
                                float* __restrict__ sft, int n) {
    int c = threadIdx.x;
    float mean = sums[c] / (float)n;
    float var = sums[128 + c] / (float)n - mean * mean;
    float rstd = rsqrtf(var + EPS);
    float sc = g[c] * rstd;
    scl[c] = sc;
    sft[c] = be[c] - mean * sc;
}

// ---------------- launch ----------------

extern "C" void kernel_launch(void* const* d_in, const int* in_sizes, int n_in,
                              void* d_out, int out_size, void* d_ws, size_t ws_size,
                              hipStream_t stream) {
    const float* x   = (const float*)d_in[0];
    const float* ew  = (const float*)d_in[1];
    const float* W0  = (const float*)d_in[2];
    const float* b0  = (const float*)d_in[3];
    const float* g0  = (const float*)d_in[4];
    const float* be0 = (const float*)d_in[5];
    const float* W1  = (const float*)d_in[6];
    const float* b1  = (const float*)d_in[7];
    const float* g1  = (const float*)d_in[8];
    const float* be1 = (const float*)d_in[9];
    const float* W2  = (const float*)d_in[10];
    const float* b2  = (const float*)d_in[11];
    const int* row   = (const int*)d_in[12];
    const int* col   = (const int*)d_in[13];

    const int N = in_sizes[0] / DD;
    const int E = in_sizes[1];
    float* out = (float*)d_out;

    char* w = (char*)d_ws;
    float* H        = (float*)w; w += (size_t)N * DD * 4;
    int*   deg      = (int*)w;   w += (size_t)N * 4;
    int*   tmp      = (int*)w;   w += (size_t)N * 4;
    int*   row_start= (int*)w;   w += (size_t)(N + 1) * 4;
    int*   cursor   = (int*)w;   w += (size_t)N * 4;
    int*   bsum     = (int*)w;   w += 128 * 4;
    int*   boff     = (int*)w;   w += 128 * 4;
    int*   csr_col  = (int*)w;   w += (size_t)E * 4;
    float* csr_w    = (float*)w; w += (size_t)E * 4;
    float* sums     = (float*)w; w += 256 * 4;
    float* scl      = (float*)w; w += 128 * 4;
    float* sft      = (float*)w; w += 128 * 4;

    // ---- CSR build (reused by all 3 SpMMs) ----
    hipMemsetAsync(deg, 0, (size_t)N * 4, stream);
    hist_kernel<<<(E + 255) / 256, 256, 0, stream>>>(row, deg, E);
    int NB = (N + 1023) / 1024;
    scanA_kernel<<<NB, 1024, 0, stream>>>(deg, tmp, bsum, N);
    scanB_kernel<<<1, 128, 0, stream>>>(bsum, boff, row_start, NB, N);
    scanC_kernel<<<NB, 1024, 0, stream>>>(deg, tmp, boff, row_start, cursor, N);
    scatter_kernel<<<(E + 255) / 256, 256, 0, stream>>>(row, col, ew, cursor, csr_col, csr_w, E);

    int gblocks = (N + 127) / 128;

    // ---- layer 0: H = x@W0+b0 ; S0 = A@H (into d_out) ----
    gemm_bn_kernel<<<gblocks, 256, 0, stream>>>(x, W0, b0, nullptr, nullptr, 0, H, N);
    spmm_kernel<<<N, 128, 0, stream>>>(H, row_start, csr_col, csr_w, out);
    hipMemsetAsync(sums, 0, 256 * 4, stream);
    bn_stats_kernel<<<256, 256, 0, stream>>>(out, sums, N);
    bn_final_kernel<<<1, 128, 0, stream>>>(sums, g0, be0, scl, sft, N);

    // ---- layer 1: H = relu(bn(S0))@W1+b1 ; S1 = A@H ----
    gemm_bn_kernel<<<gblocks, 256, 0, stream>>>(out, W1, b1, scl, sft, 1, H, N);
    spmm_kernel<<<N, 128, 0, stream>>>(H, row_start, csr_col, csr_w, out);
    hipMemsetAsync(sums, 0, 256 * 4, stream);
    bn_stats_kernel<<<256, 256, 0, stream>>>(out, sums, N);
    bn_final_kernel<<<1, 128, 0, stream>>>(sums, g1, be1, scl, sft, N);

    // ---- layer 2: H = relu(bn(S1))@W2+b2 ; out = A@H ----
    gemm_bn_kernel<<<gblocks, 256, 0, stream>>>(out, W2, b2, scl, sft, 1, H, N);
    spmm_kernel<<<N, 128, 0, stream>>>(H, row_start, csr_col, csr_w, out);
}

// Round 2
// 727.098 us; speedup vs baseline: 1.5350x; 1.5350x over previous
//
#include <hip/hip_runtime.h>
#include <cstddef>

#define DD 128
#define EPS 1e-5f

typedef short short8 __attribute__((ext_vector_type(8)));
typedef float float4v __attribute__((ext_vector_type(4)));

__device__ __forceinline__ unsigned short f2bf(float f) {
    union { float f; unsigned int u; } x; x.f = f;
    unsigned int r = x.u + 0x7fffu + ((x.u >> 16) & 1u);   // RNE
    return (unsigned short)(r >> 16);
}
__device__ __forceinline__ float bfhi2f(unsigned int hi_bits) {  // bits already in high half
    union { unsigned int u; float f; } x; x.u = hi_bits;
    return x.f;
}

// ---------------- CSR build ----------------

__global__ void hist_kernel(const int* __restrict__ row, int* __restrict__ deg, int E) {
    int e = blockIdx.x * blockDim.x + threadIdx.x;
    if (e < E) atomicAdd(&deg[row[e]], 1);
}

__global__ void scanA_kernel(const int* __restrict__ deg, int* __restrict__ tmp,
                             int* __restrict__ bsum, int n) {
    __shared__ int s[1024];
    int tid = threadIdx.x;
    int gid = blockIdx.x * 1024 + tid;
    int v = (gid < n) ? deg[gid] : 0;
    s[tid] = v;
    __syncthreads();
    for (int off = 1; off < 1024; off <<= 1) {
        int t = s[tid];
        int u = (tid >= off) ? s[tid - off] : 0;
        __syncthreads();
        s[tid] = t + u;
        __syncthreads();
    }
    if (gid < n) tmp[gid] = s[tid];
    if (tid == 1023) bsum[blockIdx.x] = s[1023];
}

__global__ void scanB_kernel(const int* __restrict__ bsum, int* __restrict__ boff,
                             int* __restrict__ row_start, int nb, int n) {
    __shared__ int s[128];
    int tid = threadIdx.x;
    int v = (tid < nb) ? bsum[tid] : 0;
    s[tid] = v;
    __syncthreads();
    for (int off = 1; off < 128; off <<= 1) {
        int t = s[tid];
        int u = (tid >= off) ? s[tid - off] : 0;
        __syncthreads();
        s[tid] = t + u;
        __syncthreads();
    }
    if (tid < nb) boff[tid] = s[tid] - v;
    if (tid == nb - 1) row_start[n] = s[tid];
}

__global__ void scanC_kernel(const int* __restrict__ deg, const int* __restrict__ tmp,
                             const int* __restrict__ boff, int* __restrict__ row_start,
                             int* __restrict__ cursor, int n) {
    int gid = blockIdx.x * 1024 + threadIdx.x;
    if (gid < n) {
        int rs = tmp[gid] - deg[gid] + boff[blockIdx.x];
        row_start[gid] = rs;
        cursor[gid] = rs;
    }
}

__global__ void scatter_kernel(const int* __restrict__ row, const int* __restrict__ col,
                               const float* __restrict__ ew, int* __restrict__ cursor,
                               int* __restrict__ csr_col, float* __restrict__ csr_w, int E) {
    int e = blockIdx.x * blockDim.x + threadIdx.x;
    if (e < E) {
        int r = row[e];
        int p = atomicAdd(&cursor[r], 1);
        csr_col[p] = col[e];
        csr_w[p] = ew[e];
    }
}

// ---------------- W -> W^T bf16 (once per launch, 3 matrices) ----------------

__global__ void convw_kernel(const float* __restrict__ W0, const float* __restrict__ W1,
                             const float* __restrict__ W2, unsigned short* __restrict__ T0,
                             unsigned short* __restrict__ T1, unsigned short* __restrict__ T2) {
    const float* W = (blockIdx.y == 0) ? W0 : (blockIdx.y == 1) ? W1 : W2;
    unsigned short* T = (blockIdx.y == 0) ? T0 : (blockIdx.y == 1) ? T1 : T2;
    int gid = blockIdx.x * 256 + threadIdx.x;   // 0..16383
    int k = gid >> 7, n = gid & 127;
    T[n * DD + k] = f2bf(W[k * DD + n]);        // T[n][k] = W[k][n]
}

// ---------------- MFMA GEMM: H_bf16 = f(A_fp32) @ W + b ----------------
// f = identity or relu(a*scale_k + shift_k).  Block: 256 thr (4 waves), 64 rows.
// Wt: bf16, layout [n][k] (B^T).  LDS rows padded to 136 elems (16B-aligned, 2-way banks).

__global__ __launch_bounds__(256) void gemm_mfma_kernel(
    const float* __restrict__ A, const unsigned short* __restrict__ Wt,
    const float* __restrict__ bias,
    const float* __restrict__ scale, const float* __restrict__ shift,
    int doBN, unsigned short* __restrict__ H, int nrows)
{
    __shared__ unsigned short Asl[64][136];
    __shared__ unsigned short Wsl[128][136];

    const int tid  = threadIdx.x;
    const int row0 = blockIdx.x * 64;

    // stage Wt (bf16, coalesced 16B chunks): 128 rows x 16 chunks
    for (int i = tid; i < 2048; i += 256) {
        int r = i >> 4, off = (i & 15) * 8;
        *(uint4*)&Wsl[r][off] = *(const uint4*)(Wt + (size_t)r * DD + off);
    }
    // stage A (fp32 -> bf16, BN+ReLU fused): 64 rows x 32 float4 chunks
    for (int i = tid; i < 2048; i += 256) {
        int r = i >> 5, off4 = i & 31;
        int grow = row0 + r;
        float4 v = make_float4(0.f, 0.f, 0.f, 0.f);
        if (grow < nrows)
            v = *(const float4*)(A + (size_t)grow * DD + off4 * 4);
        if (doBN) {
            float4 sc = *(const float4*)(scale + off4 * 4);
            float4 sh = *(const float4*)(shift + off4 * 4);
            v.x = fmaxf(0.f, v.x * sc.x + sh.x);
            v.y = fmaxf(0.f, v.y * sc.y + sh.y);
            v.z = fmaxf(0.f, v.z * sc.z + sh.z);
            v.w = fmaxf(0.f, v.w * sc.w + sh.w);
        }
        ushort4 p;
        p.x = f2bf(v.x); p.y = f2bf(v.y); p.z = f2bf(v.z); p.w = f2bf(v.w);
        *(ushort4*)&Asl[r][off4 * 4] = p;
    }
    __syncthreads();

    const int w = tid >> 6, lane = tid & 63;
    const int m = lane & 15, q = lane >> 4;

    short8 afr[4];
    #pragma unroll
    for (int c = 0; c < 4; ++c)
        afr[c] = *(const short8*)&Asl[w * 16 + m][c * 32 + q * 8];

    float4v acc[8];
    #pragma unroll
    for (int t = 0; t < 8; ++t) acc[t] = (float4v){0.f, 0.f, 0.f, 0.f};

    #pragma unroll
    for (int t = 0; t < 8; ++t) {
        #pragma unroll
        for (int c = 0; c < 4; ++c) {
            short8 bfr = *(const short8*)&Wsl[t * 16 + m][c * 32 + q * 8];
            acc[t] = __builtin_amdgcn_mfma_f32_16x16x32_bf16(afr[c], bfr, acc[t], 0, 0, 0);
        }
    }

    // epilogue: bias add, write D (bf16) back into Asl (each wave owns its 16 rows)
    #pragma unroll
    for (int t = 0; t < 8; ++t) {
        float bv = bias[t * 16 + m];
        #pragma unroll
        for (int i = 0; i < 4; ++i)
            Asl[w * 16 + q * 4 + i][t * 16 + m] = f2bf(acc[t][i] + bv);
    }
    __syncthreads();

    // coalesced copy out: 64 rows x 16 chunks of 16B
    for (int i = tid; i < 1024; i += 256) {
        int r = i >> 4, off = (i & 15) * 8;
        if (row0 + r < nrows)
            *(uint4*)(H + (size_t)(row0 + r) * DD + off) = *(const uint4*)&Asl[r][off];
    }
}

// ---------------- SpMM: S_fp32 = A_csr @ H_bf16 ----------------
// 4 rows/block, 64 lanes/row, 2 channels/lane (bf16x2 = 4B coalesced loads)

__global__ __launch_bounds__(256) void spmm_bf16_kernel(
    const unsigned short* __restrict__ H, const int* __restrict__ row_start,
    const int* __restrict__ csr_col, const float* __restrict__ csr_w,
    float* __restrict__ S, int N)
{
    int g = threadIdx.x >> 6, lane = threadIdx.x & 63;
    int r = blockIdx.x * 4 + g;
    if (r >= N) return;
    int e0 = row_start[r];
    int e1 = row_start[r + 1];
    float ax = 0.f, ay = 0.f;
    const unsigned short* Hp = H + lane * 2;
    int e = e0;
    for (; e + 1 < e1; e += 2) {
        int c0 = csr_col[e], c1 = csr_col[e + 1];
        float w0 = csr_w[e], w1 = csr_w[e + 1];
        unsigned int u0 = *(const unsigned int*)(Hp + (size_t)c0 * DD);
        unsigned int u1 = *(const unsigned int*)(Hp + (size_t)c1 * DD);
        ax += w0 * bfhi2f(u0 << 16);
        ay += w0 * bfhi2f(u0 & 0xffff0000u);
        ax += w1 * bfhi2f(u1 << 16);
        ay += w1 * bfhi2f(u1 & 0xffff0000u);
    }
    if (e < e1) {
        int c0 = csr_col[e];
        float w0 = csr_w[e];
        unsigned int u0 = *(const unsigned int*)(Hp + (size_t)c0 * DD);
        ax += w0 * bfhi2f(u0 << 16);
        ay += w0 * bfhi2f(u0 & 0xffff0000u);
    }
    float2 o; o.x = ax; o.y = ay;
    *(float2*)(S + (size_t)r * DD + lane * 2) = o;
}

// ---------------- BatchNorm stats + finalize ----------------

__global__ void bn_stats_kernel(const float* __restrict__ S, float* __restrict__ sums, int n) {
    __shared__ float ls[256], ls2[256];
    int tid = threadIdx.x;
    int c = tid & 127;
    float s = 0.f, s2 = 0.f;
    size_t total = (size_t)n * DD;
    #pragma unroll 8
    for (size_t i = (size_t)blockIdx.x * 256 + tid; i < total; i += (size_t)256 * 256) {
        float v = S[i];
        s += v;
        s2 += v * v;
    }
    ls[tid] = s;
    ls2[tid] = s2;
    __syncthreads();
    if (tid < 128) {
        s  = ls[tid] + ls[tid + 128];
        s2 = ls2[tid] + ls2[tid + 128];
        atomicAdd(&sums[c], s);
        atomicAdd(&sums[128 + c], s2);
    }
}

__global__ void bn_final_kernel(const float* __restrict__ sums, const float* __restrict__ g,
                                const float* __restrict__ be, float* __restrict__ scl,
                                float* __restrict__ sft, int n) {
    int c = threadIdx.x;
    float mean = sums[c] / (float)n;
    float var = sums[128 + c] / (float)n - mean * mean;
    float rstd = rsqrtf(var + EPS);
    float sc = g[c] * rstd;
    scl[c] = sc;
    sft[c] = be[c] - mean * sc;
}

// ---------------- launch ----------------

extern "C" void kernel_launch(void* const* d_in, const int* in_sizes, int n_in,
                              void* d_out, int out_size, void* d_ws, size_t ws_size,
                              hipStream_t stream) {
    const float* x   = (const float*)d_in[0];
    const float* ew  = (const float*)d_in[1];
    const float* W0  = (const float*)d_in[2];
    const float* b0  = (const float*)d_in[3];
    const float* g0  = (const float*)d_in[4];
    const float* be0 = (const float*)d_in[5];
    const float* W1  = (const float*)d_in[6];
    const float* b1  = (const float*)d_in[7];
    const float* g1  = (const float*)d_in[8];
    const float* be1 = (const float*)d_in[9];
    const float* W2  = (const float*)d_in[10];
    const float* b2  = (const float*)d_in[11];
    const int* row   = (const int*)d_in[12];
    const int* col   = (const int*)d_in[13];

    const int N = in_sizes[0] / DD;
    const int E = in_sizes[1];
    float* out = (float*)d_out;

    // workspace layout — all 16B-aligned offsets first
    char* w = (char*)d_ws;
    unsigned short* H   = (unsigned short*)w; w += (size_t)N * DD * 2;   // 25.6 MB
    unsigned short* Wt0 = (unsigned short*)w; w += DD * DD * 2;
    unsigned short* Wt1 = (unsigned short*)w; w += DD * DD * 2;
    unsigned short* Wt2 = (unsigned short*)w; w += DD * DD * 2;
    int*   csr_col  = (int*)w;   w += (size_t)E * 4;
    float* csr_w    = (float*)w; w += (size_t)E * 4;
    float* sums     = (float*)w; w += 256 * 4;
    float* scl      = (float*)w; w += 128 * 4;
    float* sft      = (float*)w; w += 128 * 4;
    int*   deg      = (int*)w;   w += (size_t)N * 4;
    int*   tmp      = (int*)w;   w += (size_t)N * 4;
    int*   cursor   = (int*)w;   w += (size_t)N * 4;
    int*   bsum     = (int*)w;   w += 128 * 4;
    int*   boff     = (int*)w;   w += 128 * 4;
    int*   row_start= (int*)w;   w += (size_t)(N + 1) * 4;

    // ---- CSR build (reused by all 3 SpMMs) ----
    hipMemsetAsync(deg, 0, (size_t)N * 4, stream);
    hist_kernel<<<(E + 255) / 256, 256, 0, stream>>>(row, deg, E);
    int NB = (N + 1023) / 1024;
    scanA_kernel<<<NB, 1024, 0, stream>>>(deg, tmp, bsum, N);
    scanB_kernel<<<1, 128, 0, stream>>>(bsum, boff, row_start, NB, N);
    scanC_kernel<<<NB, 1024, 0, stream>>>(deg, tmp, boff, row_start, cursor, N);
    scatter_kernel<<<(E + 255) / 256, 256, 0, stream>>>(row, col, ew, cursor, csr_col, csr_w, E);

    // ---- weights -> bf16 transposed ----
    convw_kernel<<<dim3(64, 3), 256, 0, stream>>>(W0, W1, W2, Wt0, Wt1, Wt2);

    int gblocks = (N + 63) / 64;
    int sblocks = (N + 3) / 4;

    // ---- layer 0 ----
    gemm_mfma_kernel<<<gblocks, 256, 0, stream>>>(x, Wt0, b0, nullptr, nullptr, 0, H, N);
    spmm_bf16_kernel<<<sblocks, 256, 0, stream>>>(H, row_start, csr_col, csr_w, out, N);
    hipMemsetAsync(sums, 0, 256 * 4, stream);
    bn_stats_kernel<<<256, 256, 0, stream>>>(out, sums, N);
    bn_final_kernel<<<1, 128, 0, stream>>>(sums, g0, be0, scl, sft, N);

    // ---- layer 1 ----
    gemm_mfma_kernel<<<gblocks, 256, 0, stream>>>(out, Wt1, b1, scl, sft, 1, H, N);
    spmm_bf16_kernel<<<sblocks, 256, 0, stream>>>(H, row_start, csr_col, csr_w, out, N);
    hipMemsetAsync(sums, 0, 256 * 4, stream);
    bn_stats_kernel<<<256, 256, 0, stream>>>(out, sums, N);
    bn_final_kernel<<<1, 128, 0, stream>>>(sums, g1, be1, scl, sft, N);

    // ---- layer 2 (no BN/ReLU after) ----
    gemm_mfma_kernel<<<gblocks, 256, 0, stream>>>(out, Wt2, b2, scl, sft, 1, H, N);
    spmm_bf16_kernel<<<sblocks, 256, 0, stream>>>(H, row_start, csr_col, csr_w, out, N);
}